// Round 2
// 912.765 us; speedup vs baseline: 1.0179x; 1.0179x over previous
//
#include <hip/hip_runtime.h>

// ============================================================================
// Compile-time Clebsch-Gordan tables: direct constexpr port of the reference
// Python (_su2_cg Racah formula, _q complex->real basis change, Frobenius
// normalization), so all sign conventions carry over exactly.
// ============================================================================
namespace cgen {

constexpr double csqrt(double x) {
  if (x <= 0.0) return 0.0;
  double g = x > 1.0 ? x : 1.0;
  for (int i = 0; i < 50; ++i) g = 0.5 * (g + x / g);
  return g;
}

constexpr double fact(int n) {
  double r = 1.0;
  for (int i = 2; i <= n; ++i) r *= (double)i;
  return r;
}

constexpr int imax3(int a, int b, int c) { int m = a > b ? a : b; return m > c ? m : c; }
constexpr int imin3(int a, int b, int c) { int m = a < b ? a : b; return m < c ? m : c; }

constexpr double su2_cg(int j1, int m1, int j2, int m2, int j3, int m3) {
  if (m3 != m1 + m2) return 0.0;
  const int vmin = imax3(-j1 + j2 + m3, -j1 + m1, 0);
  const int vmax = imin3(j2 + j3 + m1, j3 - j1 + j2, j3 + m3);
  const double c = csqrt((2.0 * j3 + 1.0) * fact(j3 + j1 - j2) * fact(j3 - j1 + j2) *
                         fact(j1 + j2 - j3) * fact(j3 + m3) * fact(j3 - m3) /
                         (fact(j1 + j2 + j3 + 1) * fact(j1 - m1) * fact(j1 + m1) *
                          fact(j2 - m2) * fact(j2 + m2)));
  double s = 0.0;
  for (int v = vmin; v <= vmax; ++v) {
    const double sg = ((v + j2 + m2) & 1) ? -1.0 : 1.0;
    s += sg * fact(j2 + j3 + m1 - v) * fact(j1 - m1 + v) /
         (fact(v) * fact(j3 - j1 + j2 - v) * fact(j3 + m3 - v) * fact(v + j1 - j2 - m3));
  }
  return c * s;
}

struct Cx { double re; double im; };
constexpr Cx cmul(Cx a, Cx b) { return Cx{a.re * b.re - a.im * b.im, a.re * b.im + a.im * b.re}; }

struct Q5 { Cx q[5][5]; };

constexpr Q5 qmat(int l) {
  Q5 Q{};
  for (int i = 0; i < 5; ++i)
    for (int j = 0; j < 5; ++j) Q.q[i][j] = Cx{0.0, 0.0};
  const double s2 = 1.0 / csqrt(2.0);
  for (int m = -l; m < 0; ++m) {
    Q.q[l + m][l - m] = Cx{s2, 0.0};    // col l+|m|
    Q.q[l + m][l + m] = Cx{0.0, -s2};   // col l-|m|
  }
  Q.q[l][l] = Cx{1.0, 0.0};
  for (int m = 1; m <= l; ++m) {
    const double sg = (m & 1) ? -1.0 : 1.0;
    Q.q[l + m][l + m] = Cx{sg * s2, 0.0};
    Q.q[l + m][l - m] = Cx{0.0, sg * s2};
  }
  const Cx f = (l == 0) ? Cx{1.0, 0.0} : ((l == 1) ? Cx{0.0, -1.0} : Cx{-1.0, 0.0}); // (-1j)^l
  for (int i = 0; i < 5; ++i)
    for (int j = 0; j < 5; ++j) Q.q[i][j] = cmul(f, Q.q[i][j]);
  return Q;
}

struct CGc { double c[5][5][5]; };

// Cr[j,l,m] = Re( sum_{i,k,n} Q1[i,j] Q2[k,l] conj(Q3[n,m]) C[i,k,n] ), Frobenius-normalized
constexpr CGc real_cg(int l1, int l2, int l3) {
  const int d1 = 2 * l1 + 1, d2 = 2 * l2 + 1, d3 = 2 * l3 + 1;
  double C[5][5][5] = {};
  for (int i = 0; i < d1; ++i)
    for (int j = 0; j < d2; ++j)
      for (int k = 0; k < d3; ++k)
        C[i][j][k] = su2_cg(l1, i - l1, l2, j - l2, l3, k - l3);
  const Q5 Q1 = qmat(l1), Q2 = qmat(l2), Q3 = qmat(l3);
  // stage 1: T1[i][k][m] = sum_n conj(Q3[n][m]) * C[i][k][n]
  Cx T1[5][5][5] = {};
  for (int i = 0; i < d1; ++i)
    for (int k = 0; k < d2; ++k)
      for (int m = 0; m < d3; ++m) {
        Cx s{0.0, 0.0};
        for (int n = 0; n < d3; ++n) {
          const double cv = C[i][k][n];
          s.re += Q3.q[n][m].re * cv;
          s.im += -Q3.q[n][m].im * cv;
        }
        T1[i][k][m] = s;
      }
  // stage 2: T2[i][l][m] = sum_k Q2[k][l] * T1[i][k][m]
  Cx T2[5][5][5] = {};
  for (int i = 0; i < d1; ++i)
    for (int l = 0; l < d2; ++l)
      for (int m = 0; m < d3; ++m) {
        Cx s{0.0, 0.0};
        for (int k = 0; k < d2; ++k) {
          const Cx t = cmul(Q2.q[k][l], T1[i][k][m]);
          s.re += t.re; s.im += t.im;
        }
        T2[i][l][m] = s;
      }
  // stage 3: R[j][l][m] = Re( sum_i Q1[i][j] * T2[i][l][m] )
  CGc R{};
  double norm2 = 0.0;
  for (int j = 0; j < d1; ++j)
    for (int l = 0; l < d2; ++l)
      for (int m = 0; m < d3; ++m) {
        Cx s{0.0, 0.0};
        for (int i = 0; i < d1; ++i) {
          const Cx t = cmul(Q1.q[i][j], T2[i][l][m]);
          s.re += t.re; s.im += t.im;
        }
        R.c[j][l][m] = s.re;
        norm2 += s.re * s.re;
      }
  const double inv = 1.0 / csqrt(norm2);
  for (int j = 0; j < d1; ++j)
    for (int l = 0; l < d2; ++l)
      for (int m = 0; m < d3; ++m) R.c[j][l][m] *= inv;
  return R;
}

// Path list (order matches reference PATHS):
//  p : (l1,l2,l3) io   d1 d2 d3
//  0 : (0,0,0)    0    1  1  1
//  1 : (0,1,1)    1    1  3  3
//  2 : (0,2,2)    2    1  5  5
//  3 : (1,0,1)    1    3  1  3
//  4 : (1,1,0)    0    3  3  1
//  5 : (1,1,2)    2    3  3  5
//  6 : (1,2,1)    1    3  5  3
//  7 : (2,0,2)    2    5  1  5
//  8 : (2,1,1)    1    5  3  3
//  9 : (2,2,0)    0    5  5  1
// 10 : (2,2,2)    2    5  5  5
constexpr CGc CG0  = real_cg(0, 0, 0);
constexpr CGc CG1  = real_cg(0, 1, 1);
constexpr CGc CG2  = real_cg(0, 2, 2);
constexpr CGc CG3  = real_cg(1, 0, 1);
constexpr CGc CG4  = real_cg(1, 1, 0);
constexpr CGc CG5  = real_cg(1, 1, 2);
constexpr CGc CG6  = real_cg(1, 2, 1);
constexpr CGc CG7  = real_cg(2, 0, 2);
constexpr CGc CG8  = real_cg(2, 1, 1);
constexpr CGc CG9  = real_cg(2, 2, 0);
constexpr CGc CG10 = real_cg(2, 2, 2);

struct Tables { float C[11][125]; };  // C[p][(i*d2+j)*d3+k], scaled by sqrt(2l3+1)/sqrt(fan_in)

constexpr Tables make_tables() {
  Tables T{};
  const CGc* R[11] = {&CG0, &CG1, &CG2, &CG3, &CG4, &CG5, &CG6, &CG7, &CG8, &CG9, &CG10};
  const int L3[11] = {0, 1, 2, 1, 0, 2, 1, 2, 1, 0, 2};
  const int IO[11] = {0, 1, 2, 1, 0, 2, 1, 2, 1, 0, 2};
  const int D1[11] = {1, 1, 1, 3, 3, 3, 3, 5, 5, 5, 5};
  const int D2[11] = {1, 3, 5, 1, 3, 3, 5, 1, 3, 5, 5};
  const double FAN[3] = {384.0, 512.0, 512.0};
  for (int p = 0; p < 11; ++p) {
    const int d1 = D1[p], d2 = D2[p], d3 = 2 * L3[p] + 1;
    const double s = csqrt(2.0 * L3[p] + 1.0) / csqrt(FAN[IO[p]]);
    for (int i = 0; i < d1; ++i)
      for (int j = 0; j < d2; ++j)
        for (int k = 0; k < d3; ++k)
          T.C[p][(i * d2 + j) * d3 + k] = (float)(R[p]->c[i][j][k] * s);
  }
  return T;
}

constexpr Tables H_TAB = make_tables();
__constant__ Tables G_TAB = H_TAB;

}  // namespace cgen

// ============================================================================
// Kernel: one block per sample (N=1024 blocks, 256 threads).
// Phase 1: x,y -> LDS.  Phase A: A_p[k,i] = s_p * sum_j C[i,j,k] y[j] (115 fl).
// Phase Z: z_p[u,k] = sum_i A_p[k,i] x_blk[u,i]  (128 x 35, LDS stride 37).
// Phase W (RESTRUCTURED): runtime loop over iu (16 iters, ~2 KB body, I$-
//   resident) instead of ~30 KB straight-line code. Per iteration: issue all
//   11 path loads back-to-back (11 KB in flight per wave, ~176 KB/CU >> 22 KB
//   BDP), then consume path-by-path with progressive vmcnt. acc indices stay
//   compile-time-constant.
// ============================================================================

template <int P, int D1, int D2, int D3, int YOFF, int AOFF>
__device__ inline void path_A(int t, const float* ys, float* As) {
  if (t < D1 * D3) {
    const int k = t / D1, i = t - k * D1;
    float s = 0.f;
#pragma unroll
    for (int j = 0; j < D2; ++j) s += cgen::G_TAB.C[P][(i * D2 + j) * D3 + k] * ys[YOFF + j];
    As[AOFF + t] = s;  // layout A[k*D1 + i]
  }
}

template <int D1, int D3, int XOFF, int AOFF, int COFF>
__device__ inline void path_Z(int u, const float* As, const float* xs, float* zs) {
  float xv[D1];
#pragma unroll
  for (int i = 0; i < D1; ++i) xv[i] = xs[XOFF + u * D1 + i];
#pragma unroll
  for (int k = 0; k < D3; ++k) {
    float s = 0.f;
#pragma unroll
    for (int i = 0; i < D1; ++i) s += As[AOFF + k * D1 + i] * xv[i];
    zs[u * 37 + COFF + k] = s;
  }
}

// Consume one path's float4 weight against the z-row (broadcast LDS reads).
template <int D3, int COFF, int KOFF>
__device__ inline void consume(const float4 wv, const float* __restrict__ zrow,
                               float (&acc)[4][9]) {
#pragma unroll
  for (int k = 0; k < D3; ++k) {
    const float zz = zrow[COFF + k];
    acc[0][KOFF + k] += wv.x * zz;
    acc[1][KOFF + k] += wv.y * zz;
    acc[2][KOFF + k] += wv.z * zz;
    acc[3][KOFF + k] += wv.w * zz;
  }
}

__global__ __launch_bounds__(256, 4) void etp_kernel(const float* __restrict__ X,
                                                     const float* __restrict__ Y,
                                                     const float* __restrict__ W,
                                                     float* __restrict__ O) {
  __shared__ float x_s[1152];
  __shared__ float y_s[12];
  __shared__ float A_s[116];
  __shared__ float z_s[128 * 37];  // also reused as 4x1152 reduction buffer

  const int n = blockIdx.x;
  const int t = threadIdx.x;

  // ---- Phase 1: stage x (float4) and y into LDS
  {
    const float4* xg = (const float4*)(X + (size_t)n * 1152);
    float4* xs4 = (float4*)x_s;
    for (int idx = t; idx < 288; idx += 256) xs4[idx] = xg[idx];
    if (t < 9) y_s[t] = Y[(size_t)n * 9 + t];
  }
  __syncthreads();

  // ---- Phase A: per-path small matrices (y folded in, scale baked into C)
  path_A<0, 1, 1, 1, 0, 0>(t, y_s, A_s);
  path_A<1, 1, 3, 3, 1, 1>(t, y_s, A_s);
  path_A<2, 1, 5, 5, 4, 4>(t, y_s, A_s);
  path_A<3, 3, 1, 3, 0, 9>(t, y_s, A_s);
  path_A<4, 3, 3, 1, 1, 18>(t, y_s, A_s);
  path_A<5, 3, 3, 5, 1, 21>(t, y_s, A_s);
  path_A<6, 3, 5, 3, 4, 36>(t, y_s, A_s);
  path_A<7, 5, 1, 5, 0, 45>(t, y_s, A_s);
  path_A<8, 5, 3, 3, 1, 70>(t, y_s, A_s);
  path_A<9, 5, 5, 1, 4, 85>(t, y_s, A_s);
  path_A<10, 5, 5, 5, 4, 90>(t, y_s, A_s);
  __syncthreads();

  // ---- Phase Z: z[u][col] for all 128 u, 35 cols (cols 0..34 contiguous,
  //      ordered by path p=0..10)
  {
    const int u = t & 127;
    if (t < 128) {
      path_Z<1, 1, 0, 0, 0>(u, A_s, x_s, z_s);
      path_Z<1, 3, 0, 1, 1>(u, A_s, x_s, z_s);
      path_Z<1, 5, 0, 4, 4>(u, A_s, x_s, z_s);
      path_Z<3, 3, 128, 9, 9>(u, A_s, x_s, z_s);
      path_Z<3, 1, 128, 18, 12>(u, A_s, x_s, z_s);
      path_Z<3, 5, 128, 21, 13>(u, A_s, x_s, z_s);
    } else {
      path_Z<3, 3, 128, 36, 18>(u, A_s, x_s, z_s);
      path_Z<5, 5, 512, 45, 21>(u, A_s, x_s, z_s);
      path_Z<5, 3, 512, 70, 26>(u, A_s, x_s, z_s);
      path_Z<5, 1, 512, 85, 29>(u, A_s, x_s, z_s);
      path_Z<5, 5, 512, 90, 30>(u, A_s, x_s, z_s);
    }
  }
  __syncthreads();

  // ---- Phase W: stream weights; tight runtime loop over iu.
  float acc[4][9];
#pragma unroll
  for (int a = 0; a < 4; ++a)
#pragma unroll
    for (int c = 0; c < 9; ++c) acc[a][c] = 0.f;

  const int lane = t & 31;   // w4 = lane*4
  const int ug = t >> 5;     // u-group 0..7
  const float4* Wb = (const float4*)(W + (size_t)n * 180224);

  // float4 index for path p at step iu: p*4096 + (ug + iu*8)*32 + lane
  int idx = ug * 32 + lane;  // advances by 256 float4 (4 KB) per iu

#pragma unroll 1
  for (int iu = 0; iu < 16; ++iu) {
    // Issue all 11 independent loads first (deep memory pipeline per wave).
    const float4 w0  = Wb[idx];
    const float4 w1  = Wb[idx + 1 * 4096];
    const float4 w2  = Wb[idx + 2 * 4096];
    const float4 w3  = Wb[idx + 3 * 4096];
    const float4 w4  = Wb[idx + 4 * 4096];
    const float4 w5  = Wb[idx + 5 * 4096];
    const float4 w6  = Wb[idx + 6 * 4096];
    const float4 w7  = Wb[idx + 7 * 4096];
    const float4 w8  = Wb[idx + 8 * 4096];
    const float4 w9  = Wb[idx + 9 * 4096];
    const float4 w10 = Wb[idx + 10 * 4096];

    const float* zrow = z_s + (ug + iu * 8) * 37;  // broadcast reads (free)

    consume<1, 0, 0>(w0, zrow, acc);
    consume<3, 1, 1>(w1, zrow, acc);
    consume<5, 4, 4>(w2, zrow, acc);
    consume<3, 9, 1>(w3, zrow, acc);
    consume<1, 12, 0>(w4, zrow, acc);
    consume<5, 13, 4>(w5, zrow, acc);
    consume<3, 18, 1>(w6, zrow, acc);
    consume<5, 21, 4>(w7, zrow, acc);
    consume<3, 26, 1>(w8, zrow, acc);
    consume<1, 29, 0>(w9, zrow, acc);
    consume<5, 30, 4>(w10, zrow, acc);

    idx += 256;
  }

  __syncthreads();  // all z reads done; z_s can be reused

  // ---- Reduce: pair u-groups within each wave (lane j += lane j+32)
#pragma unroll
  for (int a = 0; a < 4; ++a)
#pragma unroll
    for (int c = 0; c < 9; ++c) acc[a][c] += __shfl_down(acc[a][c], 32, 64);

  if ((t & 63) < 32) {
    const int wave = t >> 6;  // 0..3
#pragma unroll
    for (int a = 0; a < 4; ++a)
#pragma unroll
      for (int c = 0; c < 9; ++c)
        z_s[wave * 1152 + (lane * 4 + a) * 9 + c] = acc[a][c];
  }
  __syncthreads();

  // ---- Final sum over 4 wave-partials + scatter to output layout
  float* On = O + (size_t)n * 1152;
  for (int idx2 = t; idx2 < 1152; idx2 += 256) {
    const float s = z_s[idx2] + z_s[1152 + idx2] + z_s[2304 + idx2] + z_s[3456 + idx2];
    const int w = idx2 / 9;
    const int col = idx2 - 9 * w;
    int g;
    if (col == 0) g = w;                       // out0: [128 x 1]
    else if (col < 4) g = 128 + w * 3 + (col - 1);  // out1: [128 x 3]
    else g = 512 + w * 5 + (col - 4);          // out2: [128 x 5]
    On[g] = s;
  }
}

extern "C" void kernel_launch(void* const* d_in, const int* in_sizes, int n_in,
                              void* d_out, int out_size, void* d_ws, size_t ws_size,
                              hipStream_t stream) {
  const float* X = (const float*)d_in[0];
  const float* Y = (const float*)d_in[1];
  const float* W = (const float*)d_in[2];
  float* O = (float*)d_out;
  // in_sizes[] are ELEMENT counts (proven: /720896 -> n=256 failed with 3/4
  // of outputs zero; /180224 -> n=1024 passes). Weight is N x 180224 floats.
  int n = in_sizes[2] / 180224;
  if (n < 1) n = 1;
  etp_kernel<<<dim3(n), dim3(256), 0, stream>>>(X, Y, W, O);
}